// Round 8
// baseline (654.577 us; speedup 1.0000x reference)
//
#include <hip/hip_runtime.h>
#include <math.h>

#define LL 256
#define DD 768
#define HH 384
#define G4 1536
#define NWIN 4
#define NLIN 9
#define NPOS 1024        // B*L
#define PROJ_N 12288     // 8 chains * 1536
#define HSTRIDE 520      // padded LDS ks-stride (shorts): bank-spreads H writes

typedef __attribute__((ext_vector_type(8))) short short8;
typedef __attribute__((ext_vector_type(4))) short short4v;
typedef __attribute__((ext_vector_type(16))) float f32x16;

static __device__ __forceinline__ float bf2f(unsigned short u) {
    union { unsigned int i; float f; } v; v.i = ((unsigned int)u) << 16; return v.f;
}
static __device__ __forceinline__ unsigned short f2bf(float f) {
    unsigned int u = __float_as_uint(f);
    u += 0x7fff + ((u >> 16) & 1);   // round-to-nearest-even
    return (unsigned short)(u >> 16);
}
static __device__ __forceinline__ float fsig(float x) {
    return __builtin_amdgcn_rcpf(1.f + __expf(-x));
}
static __device__ __forceinline__ float ftanh(float x) {
    return 1.f - 2.f * __builtin_amdgcn_rcpf(1.f + __expf(2.f * x));
}

// ---------------------------------------------------------------- zero
__global__ void zero_f4(float4* __restrict__ p, int n4) {
    int i = blockIdx.x * blockDim.x + threadIdx.x;
    if (i < n4) p[i] = make_float4(0.f, 0.f, 0.f, 0.f);
}

// ---------------------------------------------------------------- scatter (frag layout only)
__global__ void scatter_kernel(const float* __restrict__ seq,
                               const int* __restrict__ valid,
                               unsigned short* __restrict__ xfrag) {
    const int b = blockIdx.x >> 5;
    const int chunk = blockIdx.x & 31;
    const int tid = threadIdx.x;
    __shared__ int vbuf[LL];
    __shared__ int dest[LL];
    vbuf[tid] = valid[b * LL + tid];
    __syncthreads();
    if (tid == 0) {
        int c = 0;
        for (int l = 0; l < LL; ++l) dest[l] = vbuf[l] ? c++ : -1;
    }
    __syncthreads();
    for (int l = chunk * 8; l < chunk * 8 + 8; ++l) {
        const int d = dest[l];
        if (d >= 0) {
            const float* src = seq + (size_t)(b * LL + l) * DD;
            const int pos = b * LL + d;
            const int pt = pos >> 5, pl = pos & 31;
            for (int j = tid; j < DD / 8; j += 256) {
                const float4 v0 = ((const float4*)src)[2 * j];
                const float4 v1 = ((const float4*)src)[2 * j + 1];
                short8 pv;
                pv[0] = (short)f2bf(v0.x); pv[1] = (short)f2bf(v0.y);
                pv[2] = (short)f2bf(v0.z); pv[3] = (short)f2bf(v0.w);
                pv[4] = (short)f2bf(v1.x); pv[5] = (short)f2bf(v1.y);
                pv[6] = (short)f2bf(v1.z); pv[7] = (short)f2bf(v1.w);
                *(short8*)(xfrag + ((size_t)(pt * 48 + (j >> 1)) * 512 + (pl + 32 * (j & 1)) * 8)) = pv;
            }
        }
    }
}

// ---------------------------------------------------------------- cast weights -> B-fragment layout
__global__ __launch_bounds__(256) void cast_frag(
        const float* __restrict__ srcF, const float* __restrict__ srcB,
        unsigned short* __restrict__ dst, int K) {
    __shared__ unsigned short lds[32 * 768];
    const int tid = threadIdx.x;
    const int vrow0 = blockIdx.x * 32;
    const int chain = vrow0 / G4;
    const int dir = chain >> 2, wi = chain & 3;
    const float* src = (dir ? srcB : srcF) + (size_t)(wi * G4 + (vrow0 % G4)) * K;
    const int total = 32 * K;
    for (int i = tid * 4; i < total; i += 1024) {
        const float4 v = *(const float4*)(src + i);
        lds[i + 0] = f2bf(v.x); lds[i + 1] = f2bf(v.y);
        lds[i + 2] = f2bf(v.z); lds[i + 3] = f2bf(v.w);
    }
    __syncthreads();
    const int nks = K >> 4;
    for (int slot = tid; slot < nks * 64; slot += 256) {
        const int ks = slot >> 6;
        const int lane = slot & 63;
        const int row = lane & 31;
        const int kb = ks * 16 + (lane >> 5) * 8;
        const short8 v = *(const short8*)&lds[row * K + kb];
        *(short8*)(dst + ((size_t)blockIdx.x * nks + ks) * 512 + lane * 8) = v;
    }
}

// ---------------------------------------------------------------- proj GEMM (MFMA, dist-1 prefetch)
// Block = (chain, us, mtg): 4 waves = 4 gates (share B), each wave 4 mt tiles.
// Output proj[pos][chain][u][gate] via LDS staging. Bias folded in.
__global__ __launch_bounds__(256) void proj_mfma(
        const unsigned short* __restrict__ xf,
        const unsigned short* __restrict__ wf,
        const float* __restrict__ bihf, const float* __restrict__ bhhf,
        const float* __restrict__ bihb, const float* __restrict__ bhhb,
        unsigned short* __restrict__ proj) {
    __shared__ __align__(16) unsigned short st[4 * 4096];   // 32 KB
    const int wv = threadIdx.x >> 6;        // gate
    const int lane = threadIdx.x & 63;
    const int colid = lane & 31, hq = lane >> 5;
    const int mtg = blockIdx.x & 7;
    const int cu = blockIdx.x >> 3;         // 0..95
    const int chain = cu / 12;
    const int us = cu % 12;
    const int dir = chain >> 2, wi = chain & 3;

    const unsigned short* bP = wf + (size_t)((chain * 48 + wv * 12 + us) * 48) * 512 + lane * 8;
    const unsigned short* aP = xf + (size_t)(mtg * 4 * 48) * 512 + lane * 8;

    f32x16 acc[4] = {};
    short8 bc, bn, ac[4], an[4];
    bc = *(const short8*)(bP);
#pragma unroll
    for (int i = 0; i < 4; ++i) ac[i] = *(const short8*)(aP + (i * 48) * 512);
#pragma unroll
    for (int ks = 0; ks < 48; ++ks) {
        if (ks < 47) {
            bn = *(const short8*)(bP + (ks + 1) * 512);
#pragma unroll
            for (int i = 0; i < 4; ++i)
                an[i] = *(const short8*)(aP + (i * 48 + ks + 1) * 512);
        }
        acc[0] = __builtin_amdgcn_mfma_f32_32x32x16_bf16(ac[0], bc, acc[0], 0, 0, 0);
        acc[1] = __builtin_amdgcn_mfma_f32_32x32x16_bf16(ac[1], bc, acc[1], 0, 0, 0);
        acc[2] = __builtin_amdgcn_mfma_f32_32x32x16_bf16(ac[2], bc, acc[2], 0, 0, 0);
        acc[3] = __builtin_amdgcn_mfma_f32_32x32x16_bf16(ac[3], bc, acc[3], 0, 0, 0);
        bc = bn;
#pragma unroll
        for (int i = 0; i < 4; ++i) ac[i] = an[i];
    }
    const int br = wv * HH + us * 32 + colid;
    const float bv = (dir ? bihb : bihf)[wi * G4 + br] + (dir ? bhhb : bhhf)[wi * G4 + br];
#pragma unroll
    for (int i = 0; i < 4; ++i) {
#pragma unroll
        for (int r = 0; r < 16; ++r) {
            const int row = (r & 3) + 8 * (r >> 2) + 4 * hq;
            st[i * 4096 + (row * 32 + colid) * 4 + wv] = f2bf(acc[i][r] + bv);
        }
    }
    __syncthreads();
#pragma unroll
    for (int j = 0; j < 8; ++j) {
        const int idx = j * 256 + threadIdx.x;
        const int i = idx >> 9, rem = idx & 511;
        const int pl = rem >> 4, q = rem & 15;
        const int pos = (mtg * 4 + i) * 32 + pl;
        *(int4*)(proj + (size_t)pos * PROJ_N + chain * G4 + us * 128 + q * 8) =
            ((const int4*)st)[idx];
    }
}

// ---------------------------------------------------------------- fused LSTM recurrence
// Block per (chain, 32-pos tile); 256 blocks = 1/CU; 768 thr = 12 waves.
// Dist-1 register double-buffer on W/A loads; LDS H double-buffer (1 barrier
// per step); interior blocks (pt&7 in 1..6) skip clamp/mask entirely.
__global__ __launch_bounds__(768, 3) void lstm_fused(
        const unsigned short* __restrict__ Wf,
        const unsigned short* __restrict__ proj,
        unsigned short* __restrict__ hfin) {
    const int p = blockIdx.x & 3, sub = (blockIdx.x >> 2) & 1;
    const int slot = blockIdx.x >> 3;
    const int chainA[4] = {3, 7, 2, 6};   // w=9,9,7,7
    const int chainB[4] = {0, 4, 1, 5};   // w=3,3,5,5
    const int chain = (slot < 16) ? chainA[p] : chainB[p];
    const int pt = sub * 16 + (slot & 15);
    const int dir = chain >> 2, wi = chain & 3;
    const int w = 3 + 2 * wi, half = wi + 1;
    const int tid = threadIdx.x;
    const int lane = tid & 63, wv = tid >> 6;   // wv 0..11 = unit slice
    const int colid = lane & 31, hq = lane >> 5;
    const int uu = wv * 32 + colid;
    const int m0 = pt * 32, b = m0 >> 8, l0 = m0 & 255;
    const bool interior = ((pt & 7) >= 1) && ((pt & 7) <= 6);

    __shared__ __align__(16) unsigned short Hbuf[2][24 * HSTRIDE];   // 2 x 24.4 KB
    float c[16];
#pragma unroll
    for (int r = 0; r < 16; ++r) c[r] = 0.f;

    const unsigned short* projb = proj + (size_t)(b * LL) * PROJ_N + chain * G4 + uu * 4;
    const unsigned short* Wb = Wf + (size_t)((chain * 48 + wv) * 24) * 512 + lane * 8;
    const int ksp = uu >> 4, khp = (uu >> 3) & 1, jp = uu & 7;
    const int hslot = ksp * HSTRIDE + khp * 256 + jp;   // + row*8

    for (int s = 0; s < w; ++s) {
        const int t = dir ? (w - 1 - s) : s;
        const int tmh = t - half;
        unsigned short* cur = Hbuf[s & 1];
        const unsigned short* prev = Hbuf[(s & 1) ^ 1];

        f32x16 acc0 = {}, acc1 = {}, acc2 = {}, acc3 = {};
        if (s > 0) {
            const unsigned short* Alds = prev + lane * 8;
            short8 wc0, wc1, wc2, wc3, acur, wn0, wn1, wn2, wn3, anx;
            acur = *(const short8*)(Alds);
            wc0 = *(const short8*)(Wb + 0 * 288 * 512);
            wc1 = *(const short8*)(Wb + 1 * 288 * 512);
            wc2 = *(const short8*)(Wb + 2 * 288 * 512);
            wc3 = *(const short8*)(Wb + 3 * 288 * 512);
#pragma unroll
            for (int ks = 0; ks < 24; ++ks) {
                if (ks < 23) {
                    anx = *(const short8*)(Alds + (ks + 1) * HSTRIDE);
                    wn0 = *(const short8*)(Wb + (0 * 288 + ks + 1) * 512);
                    wn1 = *(const short8*)(Wb + (1 * 288 + ks + 1) * 512);
                    wn2 = *(const short8*)(Wb + (2 * 288 + ks + 1) * 512);
                    wn3 = *(const short8*)(Wb + (3 * 288 + ks + 1) * 512);
                }
                acc0 = __builtin_amdgcn_mfma_f32_32x32x16_bf16(acur, wc0, acc0, 0, 0, 0);
                acc1 = __builtin_amdgcn_mfma_f32_32x32x16_bf16(acur, wc1, acc1, 0, 0, 0);
                acc2 = __builtin_amdgcn_mfma_f32_32x32x16_bf16(acur, wc2, acc2, 0, 0, 0);
                acc3 = __builtin_amdgcn_mfma_f32_32x32x16_bf16(acur, wc3, acc3, 0, 0, 0);
                acur = anx; wc0 = wn0; wc1 = wn1; wc2 = wn2; wc3 = wn3;
            }
        }

        if (interior) {
#pragma unroll
            for (int rc = 0; rc < 4; ++rc) {
                short4v pj[4];
#pragma unroll
                for (int q = 0; q < 4; ++q) {
                    const int row = 8 * rc + 4 * hq + q;
                    pj[q] = *(const short4v*)(projb + (l0 + row + tmh) * PROJ_N);
                }
#pragma unroll
                for (int q = 0; q < 4; ++q) {
                    const int r = rc * 4 + q;
                    const int row = 8 * rc + 4 * hq + q;
                    const float gi = acc0[r] + bf2f((unsigned short)pj[q][0]);
                    const float gf = acc1[r] + bf2f((unsigned short)pj[q][1]);
                    const float gg = acc2[r] + bf2f((unsigned short)pj[q][2]);
                    const float go = acc3[r] + bf2f((unsigned short)pj[q][3]);
                    c[r] = fsig(gf) * c[r] + fsig(gi) * ftanh(gg);
                    cur[hslot + row * 8] = f2bf(fsig(go) * ftanh(c[r]));
                }
            }
        } else {
#pragma unroll
            for (int rc = 0; rc < 4; ++rc) {
                short4v pj[4];
#pragma unroll
                for (int q = 0; q < 4; ++q) {
                    const int row = 8 * rc + 4 * hq + q;
                    int src = l0 + row + tmh;
                    src = src < 0 ? 0 : (src > LL - 1 ? LL - 1 : src);
                    pj[q] = *(const short4v*)(projb + src * PROJ_N);
                }
#pragma unroll
                for (int q = 0; q < 4; ++q) {
                    const int r = rc * 4 + q;
                    const int row = 8 * rc + 4 * hq + q;
                    const int src = l0 + row + tmh;
                    unsigned short hv;
                    if (src >= 0 && src < LL) {
                        const float gi = acc0[r] + bf2f((unsigned short)pj[q][0]);
                        const float gf = acc1[r] + bf2f((unsigned short)pj[q][1]);
                        const float gg = acc2[r] + bf2f((unsigned short)pj[q][2]);
                        const float go = acc3[r] + bf2f((unsigned short)pj[q][3]);
                        c[r] = fsig(gf) * c[r] + fsig(gi) * ftanh(gg);
                        hv = f2bf(fsig(go) * ftanh(c[r]));
                    } else {
                        hv = (s == 0) ? (unsigned short)0 : prev[hslot + row * 8];
                    }
                    cur[hslot + row * 8] = hv;
                }
            }
        }
        __syncthreads();
    }

    // ---- final H -> global (unpadded hfrag layout)
    const unsigned short* fin = Hbuf[(w - 1) & 1];
    unsigned short* ho = hfin + (size_t)chain * (NPOS * HH) + (size_t)pt * 12288;
#pragma unroll
    for (int i = tid; i < 1536; i += 768) {
        const int ks = i >> 6, off = i & 63;
        *(int4*)(ho + ks * 512 + off * 8) = *(const int4*)(fin + ks * HSTRIDE + off * 8);
    }
}

// ---------------------------------------------------------------- attention + linear head (frag-native)
// Block per pt (32 blocks, 512 thr = 8 waves). Wave (dir, kr) handles ks range
// [kr*6, kr*6+6) of the 384-dim half 'dir'. All loads are coalesced short8.
__global__ __launch_bounds__(512) void attn_out_kernel(
        const unsigned short* __restrict__ xfrag,
        const unsigned short* __restrict__ hfin,
        const float* __restrict__ lin_w, const float* __restrict__ lin_b,
        float* __restrict__ out) {
    const int pt = blockIdx.x;
    const int tid = threadIdx.x;
    const int lane = tid & 63, wv = tid >> 6;
    const int dir = wv >> 2, kr = wv & 3;
    const int pos = lane & 31, kh = lane >> 5;
    const float inv_sqrt_d = 0.03608439182435161f;

    __shared__ float scp[8][4][32];
    __shared__ float attw[4][32];
    __shared__ float redp[8][32][10];

    const unsigned short* xb = xfrag + ((size_t)(pt * 48 + 24 * dir)) * 512 + lane * 8;
    const unsigned short* hb0 = hfin + (size_t)(dir * 4) * (NPOS * HH) + (size_t)pt * 12288 + lane * 8;

    // ---- phase 1: scores
    float sc4[4] = {0.f, 0.f, 0.f, 0.f};
#pragma unroll
    for (int k = 0; k < 6; ++k) {
        const int ks = kr * 6 + k;
        const short8 xv = *(const short8*)(xb + ks * 512);
        float xf[8];
#pragma unroll
        for (int j = 0; j < 8; ++j) xf[j] = bf2f((unsigned short)xv[j]);
#pragma unroll
        for (int wi = 0; wi < 4; ++wi) {
            const short8 hv = *(const short8*)(hb0 + (size_t)wi * (NPOS * HH) + ks * 512);
#pragma unroll
            for (int j = 0; j < 8; ++j)
                sc4[wi] = fmaf(xf[j], bf2f((unsigned short)hv[j]), sc4[wi]);
        }
    }
#pragma unroll
    for (int wi = 0; wi < 4; ++wi) sc4[wi] += __shfl_down(sc4[wi], 32);
    if (lane < 32) {
#pragma unroll
        for (int wi = 0; wi < 4; ++wi) scp[wv][wi][pos] = sc4[wi];
    }
    __syncthreads();
    if (tid < 32) {
        float s[4], mx = -1e30f;
#pragma unroll
        for (int wi = 0; wi < 4; ++wi) {
            float v = 0.f;
#pragma unroll
            for (int g = 0; g < 8; ++g) v += scp[g][wi][tid];
            s[wi] = v * inv_sqrt_d;
            mx = fmaxf(mx, s[wi]);
        }
        float denom = 0.f;
#pragma unroll
        for (int wi = 0; wi < 4; ++wi) { s[wi] = __expf(s[wi] - mx); denom += s[wi]; }
        const float rd = __builtin_amdgcn_rcpf(denom);
#pragma unroll
        for (int wi = 0; wi < 4; ++wi) attw[wi][tid] = s[wi] * rd;
    }
    __syncthreads();

    // ---- phase 2: ov = x + sum_wi attw*h ; rp[r] = sum_d ov*lin_w[r][d]
    float aw[4];
#pragma unroll
    for (int wi = 0; wi < 4; ++wi) aw[wi] = attw[wi][pos];
    float rp[9];
#pragma unroll
    for (int r = 0; r < 9; ++r) rp[r] = 0.f;
#pragma unroll
    for (int k = 0; k < 6; ++k) {
        const int ks = kr * 6 + k;
        const short8 xv = *(const short8*)(xb + ks * 512);
        float ov[8];
#pragma unroll
        for (int j = 0; j < 8; ++j) ov[j] = bf2f((unsigned short)xv[j]);
#pragma unroll
        for (int wi = 0; wi < 4; ++wi) {
            const short8 hv = *(const short8*)(hb0 + (size_t)wi * (NPOS * HH) + ks * 512);
#pragma unroll
            for (int j = 0; j < 8; ++j)
                ov[j] = fmaf(aw[wi], bf2f((unsigned short)hv[j]), ov[j]);
        }
        const int dbase = dir * 384 + ks * 16 + kh * 8;
#pragma unroll
        for (int r = 0; r < 9; ++r) {
            const float4 lw0 = *(const float4*)(lin_w + r * DD + dbase);
            const float4 lw1 = *(const float4*)(lin_w + r * DD + dbase + 4);
            rp[r] += ov[0] * lw0.x + ov[1] * lw0.y + ov[2] * lw0.z + ov[3] * lw0.w
                   + ov[4] * lw1.x + ov[5] * lw1.y + ov[6] * lw1.z + ov[7] * lw1.w;
        }
    }
#pragma unroll
    for (int r = 0; r < 9; ++r) rp[r] += __shfl_down(rp[r], 32);
    if (lane < 32) {
#pragma unroll
        for (int r = 0; r < 9; ++r) redp[wv][pos][r] = rp[r];
    }
    __syncthreads();
    if (tid < 288) {
        const int p2 = tid / 9, r = tid % 9;
        float s = lin_b[r];
#pragma unroll
        for (int g = 0; g < 8; ++g) s += redp[g][p2][r];
        out[(size_t)(pt * 32 + p2) * NLIN + r] = s;
    }
}

// ---------------------------------------------------------------- launch
extern "C" void kernel_launch(void* const* d_in, const int* in_sizes, int n_in,
                              void* d_out, int out_size, void* d_ws, size_t ws_size,
                              hipStream_t stream) {
    (void)in_sizes; (void)n_in; (void)out_size; (void)ws_size;
    const float* seq   = (const float*)d_in[0];
    const int*   valid = (const int*)d_in[1];
    const float* wih_f = (const float*)d_in[2];
    const float* whh_f = (const float*)d_in[3];
    const float* bih_f = (const float*)d_in[4];
    const float* bhh_f = (const float*)d_in[5];
    const float* wih_b = (const float*)d_in[6];
    const float* whh_b = (const float*)d_in[7];
    const float* bih_b = (const float*)d_in[8];
    const float* bhh_b = (const float*)d_in[9];
    const float* lin_w = (const float*)d_in[10];
    const float* lin_b = (const float*)d_in[11];
    float* out = (float*)d_out;

    // workspace layout (~60 MB)
    unsigned short* xfrag = (unsigned short*)d_ws;                 // 786432 bf16
    unsigned short* proj  = xfrag + (size_t)NPOS * DD;             // 12582912 bf16
    unsigned short* wfhh  = proj + (size_t)NPOS * PROJ_N;          // 4718592 bf16
    unsigned short* wfih  = wfhh + (size_t)4718592;                // 9437184 bf16
    unsigned short* hfin  = wfih + (size_t)9437184;                // 3145728 bf16

    zero_f4<<<(98304 + 255) / 256, 256, 0, stream>>>((float4*)xfrag, 98304);
    scatter_kernel<<<128, 256, 0, stream>>>(seq, valid, xfrag);
    cast_frag<<<384, 256, 0, stream>>>(wih_f, wih_b, wfih, DD);
    cast_frag<<<384, 256, 0, stream>>>(whh_f, whh_b, wfhh, HH);
    proj_mfma<<<768, 256, 0, stream>>>(xfrag, wfih, bih_f, bhh_f, bih_b, bhh_b, proj);
    lstm_fused<<<256, 768, 0, stream>>>(wfhh, proj, hfin);
    attn_out_kernel<<<32, 512, 0, stream>>>(xfrag, hfin, lin_w, lin_b, out);
}

// Round 9
// 306.723 us; speedup vs baseline: 2.1341x; 2.1341x over previous
//
#include <hip/hip_runtime.h>
#include <math.h>

#define LL 256
#define DD 768
#define HH 384
#define G4 1536
#define NWIN 4
#define NLIN 9
#define NPOS 1024        // B*L
#define PROJ_N 12288     // 8 chains * 1536
#define HSTRIDE 520      // padded LDS ks-stride (shorts): bank-spreads H writes

typedef __attribute__((ext_vector_type(8))) short short8;
typedef __attribute__((ext_vector_type(4))) short short4v;
typedef __attribute__((ext_vector_type(16))) float f32x16;

static __device__ __forceinline__ float bf2f(unsigned short u) {
    union { unsigned int i; float f; } v; v.i = ((unsigned int)u) << 16; return v.f;
}
static __device__ __forceinline__ unsigned short f2bf(float f) {
    unsigned int u = __float_as_uint(f);
    u += 0x7fff + ((u >> 16) & 1);   // round-to-nearest-even
    return (unsigned short)(u >> 16);
}
static __device__ __forceinline__ float fsig(float x) {
    return __builtin_amdgcn_rcpf(1.f + __expf(-x));
}
static __device__ __forceinline__ float ftanh(float x) {
    return 1.f - 2.f * __builtin_amdgcn_rcpf(1.f + __expf(2.f * x));
}

// ---------------------------------------------------------------- zero
__global__ void zero_f4(float4* __restrict__ p, int n4) {
    int i = blockIdx.x * blockDim.x + threadIdx.x;
    if (i < n4) p[i] = make_float4(0.f, 0.f, 0.f, 0.f);
}

// ---------------------------------------------------------------- scatter (frag layout only)
__global__ void scatter_kernel(const float* __restrict__ seq,
                               const int* __restrict__ valid,
                               unsigned short* __restrict__ xfrag) {
    const int b = blockIdx.x >> 5;
    const int chunk = blockIdx.x & 31;
    const int tid = threadIdx.x;
    __shared__ int vbuf[LL];
    __shared__ int dest[LL];
    vbuf[tid] = valid[b * LL + tid];
    __syncthreads();
    if (tid == 0) {
        int c = 0;
        for (int l = 0; l < LL; ++l) dest[l] = vbuf[l] ? c++ : -1;
    }
    __syncthreads();
    for (int l = chunk * 8; l < chunk * 8 + 8; ++l) {
        const int d = dest[l];
        if (d >= 0) {
            const float* src = seq + (size_t)(b * LL + l) * DD;
            const int pos = b * LL + d;
            const int pt = pos >> 5, pl = pos & 31;
            for (int j = tid; j < DD / 8; j += 256) {
                const float4 v0 = ((const float4*)src)[2 * j];
                const float4 v1 = ((const float4*)src)[2 * j + 1];
                short8 pv;
                pv[0] = (short)f2bf(v0.x); pv[1] = (short)f2bf(v0.y);
                pv[2] = (short)f2bf(v0.z); pv[3] = (short)f2bf(v0.w);
                pv[4] = (short)f2bf(v1.x); pv[5] = (short)f2bf(v1.y);
                pv[6] = (short)f2bf(v1.z); pv[7] = (short)f2bf(v1.w);
                *(short8*)(xfrag + ((size_t)(pt * 48 + (j >> 1)) * 512 + (pl + 32 * (j & 1)) * 8)) = pv;
            }
        }
    }
}

// ---------------------------------------------------------------- cast weights -> B-fragment layout
__global__ __launch_bounds__(256) void cast_frag(
        const float* __restrict__ srcF, const float* __restrict__ srcB,
        unsigned short* __restrict__ dst, int K) {
    __shared__ unsigned short lds[32 * 768];
    const int tid = threadIdx.x;
    const int vrow0 = blockIdx.x * 32;
    const int chain = vrow0 / G4;
    const int dir = chain >> 2, wi = chain & 3;
    const float* src = (dir ? srcB : srcF) + (size_t)(wi * G4 + (vrow0 % G4)) * K;
    const int total = 32 * K;
    for (int i = tid * 4; i < total; i += 1024) {
        const float4 v = *(const float4*)(src + i);
        lds[i + 0] = f2bf(v.x); lds[i + 1] = f2bf(v.y);
        lds[i + 2] = f2bf(v.z); lds[i + 3] = f2bf(v.w);
    }
    __syncthreads();
    const int nks = K >> 4;
    for (int slot = tid; slot < nks * 64; slot += 256) {
        const int ks = slot >> 6;
        const int lane = slot & 63;
        const int row = lane & 31;
        const int kb = ks * 16 + (lane >> 5) * 8;
        const short8 v = *(const short8*)&lds[row * K + kb];
        *(short8*)(dst + ((size_t)blockIdx.x * nks + ks) * 512 + lane * 8) = v;
    }
}

// ---------------------------------------------------------------- proj GEMM (MFMA, dist-1 prefetch)
// Block = (chain, us, mtg): 4 waves = 4 gates (share B), each wave 4 mt tiles.
// Output proj[pos][chain][u][gate] via LDS staging. Bias folded in.
__global__ __launch_bounds__(256) void proj_mfma(
        const unsigned short* __restrict__ xf,
        const unsigned short* __restrict__ wf,
        const float* __restrict__ bihf, const float* __restrict__ bhhf,
        const float* __restrict__ bihb, const float* __restrict__ bhhb,
        unsigned short* __restrict__ proj) {
    __shared__ __align__(16) unsigned short st[4 * 4096];   // 32 KB
    const int wv = threadIdx.x >> 6;        // gate
    const int lane = threadIdx.x & 63;
    const int colid = lane & 31, hq = lane >> 5;
    const int mtg = blockIdx.x & 7;
    const int cu = blockIdx.x >> 3;         // 0..95
    const int chain = cu / 12;
    const int us = cu % 12;
    const int dir = chain >> 2, wi = chain & 3;

    const unsigned short* bP = wf + (size_t)((chain * 48 + wv * 12 + us) * 48) * 512 + lane * 8;
    const unsigned short* aP = xf + (size_t)(mtg * 4 * 48) * 512 + lane * 8;

    f32x16 acc[4] = {};
#pragma unroll 4
    for (int ks = 0; ks < 48; ++ks) {
        const short8 bv = *(const short8*)(bP + ks * 512);
        const short8 a0 = *(const short8*)(aP + (0 * 48 + ks) * 512);
        const short8 a1 = *(const short8*)(aP + (1 * 48 + ks) * 512);
        const short8 a2 = *(const short8*)(aP + (2 * 48 + ks) * 512);
        const short8 a3 = *(const short8*)(aP + (3 * 48 + ks) * 512);
        acc[0] = __builtin_amdgcn_mfma_f32_32x32x16_bf16(a0, bv, acc[0], 0, 0, 0);
        acc[1] = __builtin_amdgcn_mfma_f32_32x32x16_bf16(a1, bv, acc[1], 0, 0, 0);
        acc[2] = __builtin_amdgcn_mfma_f32_32x32x16_bf16(a2, bv, acc[2], 0, 0, 0);
        acc[3] = __builtin_amdgcn_mfma_f32_32x32x16_bf16(a3, bv, acc[3], 0, 0, 0);
    }
    const int br = wv * HH + us * 32 + colid;
    const float bv = (dir ? bihb : bihf)[wi * G4 + br] + (dir ? bhhb : bhhf)[wi * G4 + br];
#pragma unroll
    for (int i = 0; i < 4; ++i) {
#pragma unroll
        for (int r = 0; r < 16; ++r) {
            const int row = (r & 3) + 8 * (r >> 2) + 4 * hq;
            st[i * 4096 + (row * 32 + colid) * 4 + wv] = f2bf(acc[i][r] + bv);
        }
    }
    __syncthreads();
#pragma unroll
    for (int j = 0; j < 8; ++j) {
        const int idx = j * 256 + threadIdx.x;
        const int i = idx >> 9, rem = idx & 511;
        const int pl = rem >> 4, q = rem & 15;
        const int pos = (mtg * 4 + i) * 32 + pl;
        *(int4*)(proj + (size_t)pos * PROJ_N + chain * G4 + us * 128 + q * 8) =
            ((const int4*)st)[idx];
    }
}

// ---------------------------------------------------------------- fused LSTM recurrence
// Block per (chain, 32-pos tile); 256 blocks = 1/CU; 768 thr = 12 waves.
// H in LDS double-buffer (1 barrier/step, padded stride), C in regs.
// proj loads are NONTEMPORAL: the 3.1 MB/step/XCD proj stream was evicting
// the 2.36 MB W slice from L2 every step (r7 FETCH evidence) -> W now L2-hit.
__global__ __launch_bounds__(768, 3) void lstm_fused(
        const unsigned short* __restrict__ Wf,
        const unsigned short* __restrict__ proj,
        unsigned short* __restrict__ hfin) {
    const int p = blockIdx.x & 3, sub = (blockIdx.x >> 2) & 1;
    const int slot = blockIdx.x >> 3;
    const int chainA[4] = {3, 7, 2, 6};   // w=9,9,7,7
    const int chainB[4] = {0, 4, 1, 5};   // w=3,3,5,5
    const int chain = (slot < 16) ? chainA[p] : chainB[p];
    const int pt = sub * 16 + (slot & 15);
    const int dir = chain >> 2, wi = chain & 3;
    const int w = 3 + 2 * wi, half = wi + 1;
    const int tid = threadIdx.x;
    const int lane = tid & 63, wv = tid >> 6;   // wv 0..11 = unit slice
    const int colid = lane & 31, hq = lane >> 5;
    const int uu = wv * 32 + colid;
    const int m0 = pt * 32, b = m0 >> 8, l0 = m0 & 255;

    __shared__ __align__(16) unsigned short Hbuf[2][24 * HSTRIDE];
    float c[16];
#pragma unroll
    for (int r = 0; r < 16; ++r) c[r] = 0.f;

    const unsigned short* projb = proj + (size_t)(b * LL) * PROJ_N + chain * G4 + uu * 4;
    const unsigned short* Wb = Wf + (size_t)((chain * 48 + wv) * 24) * 512 + lane * 8;
    const int ksp = uu >> 4, khp = (uu >> 3) & 1, jp = uu & 7;
    const int hslot = ksp * HSTRIDE + khp * 256 + jp;   // + row*8

    for (int s = 0; s < w; ++s) {
        const int t = dir ? (w - 1 - s) : s;
        const int tmh = t - half;
        unsigned short* cur = Hbuf[s & 1];
        const unsigned short* prev = Hbuf[(s & 1) ^ 1];

        // ---- gate-packed proj prefetch: NONTEMPORAL (don't evict W from L2)
        short4v pj[16];
#pragma unroll
        for (int r = 0; r < 16; ++r) {
            const int row = (r & 3) + 8 * (r >> 2) + 4 * hq;
            int src = l0 + row + tmh;
            src = src < 0 ? 0 : (src > LL - 1 ? LL - 1 : src);
            pj[r] = __builtin_nontemporal_load((const short4v*)(projb + src * PROJ_N));
        }

        f32x16 acc0 = {}, acc1 = {}, acc2 = {}, acc3 = {};
        if (s > 0) {   // s==0: H is zero, gates = proj only
            const unsigned short* Alds = prev + lane * 8;
#pragma unroll 4
            for (int ks = 0; ks < 24; ++ks) {
                const short8 av  = *(const short8*)(Alds + ks * HSTRIDE);
                const short8 bv0 = *(const short8*)(Wb + (size_t)(0 * 288 + ks) * 512);
                const short8 bv1 = *(const short8*)(Wb + (size_t)(1 * 288 + ks) * 512);
                const short8 bv2 = *(const short8*)(Wb + (size_t)(2 * 288 + ks) * 512);
                const short8 bv3 = *(const short8*)(Wb + (size_t)(3 * 288 + ks) * 512);
                acc0 = __builtin_amdgcn_mfma_f32_32x32x16_bf16(av, bv0, acc0, 0, 0, 0);
                acc1 = __builtin_amdgcn_mfma_f32_32x32x16_bf16(av, bv1, acc1, 0, 0, 0);
                acc2 = __builtin_amdgcn_mfma_f32_32x32x16_bf16(av, bv2, acc2, 0, 0, 0);
                acc3 = __builtin_amdgcn_mfma_f32_32x32x16_bf16(av, bv3, acc3, 0, 0, 0);
            }
        }

#pragma unroll
        for (int r = 0; r < 16; ++r) {
            const int row = (r & 3) + 8 * (r >> 2) + 4 * hq;
            const int src = l0 + row + tmh;
            unsigned short hv;
            if (src >= 0 && src < LL) {
                const float gi = acc0[r] + bf2f((unsigned short)pj[r][0]);
                const float gf = acc1[r] + bf2f((unsigned short)pj[r][1]);
                const float gg = acc2[r] + bf2f((unsigned short)pj[r][2]);
                const float go = acc3[r] + bf2f((unsigned short)pj[r][3]);
                c[r] = fsig(gf) * c[r] + fsig(gi) * ftanh(gg);
                hv = f2bf(fsig(go) * ftanh(c[r]));
            } else {
                hv = (s == 0) ? (unsigned short)0 : prev[hslot + row * 8];
            }
            cur[hslot + row * 8] = hv;
        }
        __syncthreads();   // writes visible before next step's reads
    }

    // ---- final H -> global (unpadded hfrag layout)
    const unsigned short* fin = Hbuf[(w - 1) & 1];
    unsigned short* ho = hfin + (size_t)chain * (NPOS * HH) + (size_t)pt * 12288;
#pragma unroll
    for (int i = tid; i < 1536; i += 768) {
        const int ks = i >> 6, off = i & 63;
        *(int4*)(ho + ks * 512 + off * 8) = *(const int4*)(fin + ks * HSTRIDE + off * 8);
    }
}

// ---------------------------------------------------------------- attention + linear head (frag-native)
__global__ __launch_bounds__(512) void attn_out_kernel(
        const unsigned short* __restrict__ xfrag,
        const unsigned short* __restrict__ hfin,
        const float* __restrict__ lin_w, const float* __restrict__ lin_b,
        float* __restrict__ out) {
    const int pt = blockIdx.x;
    const int tid = threadIdx.x;
    const int lane = tid & 63, wv = tid >> 6;
    const int dir = wv >> 2, kr = wv & 3;
    const int pos = lane & 31, kh = lane >> 5;
    const float inv_sqrt_d = 0.03608439182435161f;

    __shared__ float scp[8][4][32];
    __shared__ float attw[4][32];
    __shared__ float redp[8][32][10];

    const unsigned short* xb = xfrag + ((size_t)(pt * 48 + 24 * dir)) * 512 + lane * 8;
    const unsigned short* hb0 = hfin + (size_t)(dir * 4) * (NPOS * HH) + (size_t)pt * 12288 + lane * 8;

    // ---- phase 1: scores
    float sc4[4] = {0.f, 0.f, 0.f, 0.f};
#pragma unroll
    for (int k = 0; k < 6; ++k) {
        const int ks = kr * 6 + k;
        const short8 xv = *(const short8*)(xb + ks * 512);
        float xf[8];
#pragma unroll
        for (int j = 0; j < 8; ++j) xf[j] = bf2f((unsigned short)xv[j]);
#pragma unroll
        for (int wi = 0; wi < 4; ++wi) {
            const short8 hv = *(const short8*)(hb0 + (size_t)wi * (NPOS * HH) + ks * 512);
#pragma unroll
            for (int j = 0; j < 8; ++j)
                sc4[wi] = fmaf(xf[j], bf2f((unsigned short)hv[j]), sc4[wi]);
        }
    }
#pragma unroll
    for (int wi = 0; wi < 4; ++wi) sc4[wi] += __shfl_down(sc4[wi], 32);
    if (lane < 32) {
#pragma unroll
        for (int wi = 0; wi < 4; ++wi) scp[wv][wi][pos] = sc4[wi];
    }
    __syncthreads();
    if (tid < 32) {
        float s[4], mx = -1e30f;
#pragma unroll
        for (int wi = 0; wi < 4; ++wi) {
            float v = 0.f;
#pragma unroll
            for (int g = 0; g < 8; ++g) v += scp[g][wi][tid];
            s[wi] = v * inv_sqrt_d;
            mx = fmaxf(mx, s[wi]);
        }
        float denom = 0.f;
#pragma unroll
        for (int wi = 0; wi < 4; ++wi) { s[wi] = __expf(s[wi] - mx); denom += s[wi]; }
        const float rd = __builtin_amdgcn_rcpf(denom);
#pragma unroll
        for (int wi = 0; wi < 4; ++wi) attw[wi][tid] = s[wi] * rd;
    }
    __syncthreads();

    // ---- phase 2: ov = x + sum_wi attw*h ; rp[r] = sum_d ov*lin_w[r][d]
    float aw[4];
#pragma unroll
    for (int wi = 0; wi < 4; ++wi) aw[wi] = attw[wi][pos];
    float rp[9];
#pragma unroll
    for (int r = 0; r < 9; ++r) rp[r] = 0.f;
#pragma unroll
    for (int k = 0; k < 6; ++k) {
        const int ks = kr * 6 + k;
        const short8 xv = *(const short8*)(xb + ks * 512);
        float ov[8];
#pragma unroll
        for (int j = 0; j < 8; ++j) ov[j] = bf2f((unsigned short)xv[j]);
#pragma unroll
        for (int wi = 0; wi < 4; ++wi) {
            const short8 hv = *(const short8*)(hb0 + (size_t)wi * (NPOS * HH) + ks * 512);
#pragma unroll
            for (int j = 0; j < 8; ++j)
                ov[j] = fmaf(aw[wi], bf2f((unsigned short)hv[j]), ov[j]);
        }
        const int dbase = dir * 384 + ks * 16 + kh * 8;
#pragma unroll
        for (int r = 0; r < 9; ++r) {
            const float4 lw0 = *(const float4*)(lin_w + r * DD + dbase);
            const float4 lw1 = *(const float4*)(lin_w + r * DD + dbase + 4);
            rp[r] += ov[0] * lw0.x + ov[1] * lw0.y + ov[2] * lw0.z + ov[3] * lw0.w
                   + ov[4] * lw1.x + ov[5] * lw1.y + ov[6] * lw1.z + ov[7] * lw1.w;
        }
    }
#pragma unroll
    for (int r = 0; r < 9; ++r) rp[r] += __shfl_down(rp[r], 32);
    if (lane < 32) {
#pragma unroll
        for (int r = 0; r < 9; ++r) redp[wv][pos][r] = rp[r];
    }
    __syncthreads();
    if (tid < 288) {
        const int p2 = tid / 9, r = tid % 9;
        float s = lin_b[r];
#pragma unroll
        for (int g = 0; g < 8; ++g) s += redp[g][p2][r];
        out[(size_t)(pt * 32 + p2) * NLIN + r] = s;
    }
}

// ---------------------------------------------------------------- launch
extern "C" void kernel_launch(void* const* d_in, const int* in_sizes, int n_in,
                              void* d_out, int out_size, void* d_ws, size_t ws_size,
                              hipStream_t stream) {
    (void)in_sizes; (void)n_in; (void)out_size; (void)ws_size;
    const float* seq   = (const float*)d_in[0];
    const int*   valid = (const int*)d_in[1];
    const float* wih_f = (const float*)d_in[2];
    const float* whh_f = (const float*)d_in[3];
    const float* bih_f = (const float*)d_in[4];
    const float* bhh_f = (const float*)d_in[5];
    const float* wih_b = (const float*)d_in[6];
    const float* whh_b = (const float*)d_in[7];
    const float* bih_b = (const float*)d_in[8];
    const float* bhh_b = (const float*)d_in[9];
    const float* lin_w = (const float*)d_in[10];
    const float* lin_b = (const float*)d_in[11];
    float* out = (float*)d_out;

    // workspace layout (~60 MB)
    unsigned short* xfrag = (unsigned short*)d_ws;                 // 786432 bf16
    unsigned short* proj  = xfrag + (size_t)NPOS * DD;             // 12582912 bf16
    unsigned short* wfhh  = proj + (size_t)NPOS * PROJ_N;          // 4718592 bf16
    unsigned short* wfih  = wfhh + (size_t)4718592;                // 9437184 bf16
    unsigned short* hfin  = wfih + (size_t)9437184;                // 3145728 bf16

    zero_f4<<<(98304 + 255) / 256, 256, 0, stream>>>((float4*)xfrag, 98304);
    scatter_kernel<<<128, 256, 0, stream>>>(seq, valid, xfrag);
    cast_frag<<<384, 256, 0, stream>>>(wih_f, wih_b, wfih, DD);
    cast_frag<<<384, 256, 0, stream>>>(whh_f, whh_b, wfhh, HH);
    proj_mfma<<<768, 256, 0, stream>>>(xfrag, wfih, bih_f, bhh_f, bih_b, bhh_b, proj);
    lstm_fused<<<256, 768, 0, stream>>>(wfhh, proj, hfin);
    attn_out_kernel<<<32, 512, 0, stream>>>(xfrag, hfin, lin_w, lin_b, out);
}